// Round 2
// baseline (298.170 us; speedup 1.0000x reference)
//
#include <hip/hip_runtime.h>
#include <hip/hip_bf16.h>

#define T_TOK 8192
#define NEXP 8
#define DMODEL 1024
#define DHID 4096

typedef __bf16 bf16x8_t __attribute__((ext_vector_type(8)));
typedef float f32x4_t __attribute__((ext_vector_type(4)));

__device__ __forceinline__ unsigned short f2bf(float f) {
    union { float f; unsigned int u; } x;
    x.f = f;
    unsigned int r = x.u + 0x7fffu + ((x.u >> 16) & 1u);  // RNE
    return (unsigned short)(r >> 16);
}

// elementwise f32 -> bf16, 4 per thread
__global__ __launch_bounds__(256) void k_cvt(const float4* __restrict__ in,
                                             ushort4* __restrict__ out, int n4) {
    int i = blockIdx.x * 256 + threadIdx.x;
    if (i >= n4) return;
    float4 v = in[i];
    ushort4 o;
    o.x = f2bf(v.x); o.y = f2bf(v.y); o.z = f2bf(v.z); o.w = f2bf(v.w);
    out[i] = o;
}

// transpose + convert: in [E][K][N] f32 -> out [E][N][K] bf16, 32x32 tiles
__global__ __launch_bounds__(256) void k_transpose_cvt(const float* __restrict__ in,
                                                       unsigned short* __restrict__ out,
                                                       int K, int N) {
    __shared__ float tile[32][33];
    int e = blockIdx.z;
    int k0 = blockIdx.y << 5;
    int n0 = blockIdx.x << 5;
    int t = threadIdx.x;
    int r = t >> 3;
    int c = (t & 7) << 2;
    const float* src = in + ((size_t)e * K + (k0 + r)) * N + n0 + c;
    float4 v = *(const float4*)src;
    tile[r][c + 0] = v.x; tile[r][c + 1] = v.y; tile[r][c + 2] = v.z; tile[r][c + 3] = v.w;
    __syncthreads();
    ushort4 o;
    o.x = f2bf(tile[c + 0][r]);
    o.y = f2bf(tile[c + 1][r]);
    o.z = f2bf(tile[c + 2][r]);
    o.w = f2bf(tile[c + 3][r]);
    unsigned short* dst = out + ((size_t)e * N + (n0 + r)) * K + k0 + c;
    *(ushort4*)dst = o;
}

// ---------------------------------------------------------------------------
// Grouped GEMM, 256xBN tile, BK=64, 8 waves (2 row x 4 col), 512 threads.
// Deep-pipelined phase schedule (T3+T4+T5 on top of T2 swizzle):
//   per phase: ds_read quadrant frags | issue 1/NPH of next tile's
//   global_load_lds -> raw s_barrier -> setprio(1) 16 MFMA setprio(0)
//   -> raw s_barrier.  vmcnt(0)+barrier ONCE per K-tile (loads had the whole
//   tile's MFMA to land; no per-stage __syncthreads drain).
// Race-freedom: stages write only buf[cur^1], reads only buf[cur]; the single
// tile-end {vmcnt(0); s_barrier; sched_barrier} publishes buf[cur^1].
// ---------------------------------------------------------------------------
template<int K, int N, int BN, int NPH, bool GELU>
__global__ __launch_bounds__(512, 2) void k_gemm256(const unsigned short* __restrict__ A,
                                                    const unsigned short* __restrict__ Bt,
                                                    void* __restrict__ C) {
    constexpr int BM = 256;
    constexpr int NT = K / 64;               // K-tiles of BK=64
    constexpr int N_REP = BN / 4 / 16;       // per-wave col frags (4 col-waves)
    constexpr int NF = (NPH == 4) ? N_REP / 2 : N_REP;   // n-frags per phase
    constexpr int nA = BM / 64;              // global_load_lds issues per tile
    constexpr int nB = BN / 64;
    constexpr int aA = nA / NPH;             // issues per phase
    constexpr int aB = nB / NPH;
    constexpr int NTN = N / BN;
    constexpr int WCOLS = BN / 4;
    constexpr int NWG = (T_TOK / BM) * NTN;

    __shared__ __align__(16) char As[2 * BM * 128];
    __shared__ __align__(16) char Bs[2 * BN * 128];

    const int tid = threadIdx.x;
    const int lane = tid & 63;
    const int wid = tid >> 6;
    const int wr = wid >> 2;        // 0..1
    const int wc = wid & 3;         // 0..3

    // bijective XCD swizzle (NWG % 8 == 0)
    const int bid = blockIdx.x;
    const int s = (bid & 7) * (NWG / 8) + (bid >> 3);
    const int nt = s % NTN;
    const int mt = s / NTN;
    const int e = mt >> 2;          // 1024 tokens/expert, BM=256

    const char* Ab = (const char*)(A + (size_t)mt * BM * K);
    const char* Bb = (const char*)(Bt + ((size_t)e * N + (size_t)nt * BN) * K);

    f32x4_t acc[8][N_REP] = {};

    auto stageA = [&](int kt, int buf, int i) {
        const int slot = i * 512 + tid;                         // 16B slots
        const int row = slot >> 3;
        const int scb = ((slot & 7) << 4) ^ ((row & 7) << 4);   // inverse-swizzled src
        __builtin_amdgcn_global_load_lds(
            (const __attribute__((address_space(1))) void*)(Ab + (size_t)row * (K * 2) + (size_t)kt * 128 + scb),
            (__attribute__((address_space(3))) void*)(As + buf * (BM * 128) + i * 8192 + wid * 1024),
            16, 0, 0);
    };
    auto stageB = [&](int kt, int buf, int i) {
        const int slot = i * 512 + tid;
        const int row = slot >> 3;
        const int scb = ((slot & 7) << 4) ^ ((row & 7) << 4);
        __builtin_amdgcn_global_load_lds(
            (const __attribute__((address_space(1))) void*)(Bb + (size_t)row * (K * 2) + (size_t)kt * 128 + scb),
            (__attribute__((address_space(3))) void*)(Bs + buf * (BN * 128) + i * 8192 + wid * 1024),
            16, 0, 0);
    };

    // prologue: stage tile 0 into buf 0, publish
    #pragma unroll
    for (int i = 0; i < nA; ++i) stageA(0, 0, i);
    #pragma unroll
    for (int i = 0; i < nB; ++i) stageB(0, 0, i);
    asm volatile("s_waitcnt vmcnt(0)" ::: "memory");
    __builtin_amdgcn_s_barrier();
    __builtin_amdgcn_sched_barrier(0);

    for (int kt = 0; kt < NT; ++kt) {
        const int cur = kt & 1;
        const int nxt = cur ^ 1;
        const char* Asb = As + cur * (BM * 128);
        const char* Bsb = Bs + cur * (BN * 128);
        const bool pf = (kt + 1 < NT);
        #pragma unroll
        for (int q = 0; q < NPH; ++q) {
            const int qm = (NPH == 4) ? (q >> 1) : q;
            const int qn = (NPH == 4) ? (q & 1) : 0;
            bf16x8_t af[2][4], bv[2][NF];
            #pragma unroll
            for (int kk = 0; kk < 2; ++kk) {
                #pragma unroll
                for (int m = 0; m < 4; ++m) {
                    const int row = wr * 128 + (qm * 4 + m) * 16 + (lane & 15);
                    const int cb = (kk * 64 + ((lane >> 4) << 4)) ^ ((row & 7) << 4);
                    af[kk][m] = *(const bf16x8_t*)(Asb + row * 128 + cb);
                }
                #pragma unroll
                for (int n = 0; n < NF; ++n) {
                    const int row = wc * WCOLS + (qn * NF + n) * 16 + (lane & 15);
                    const int cb = (kk * 64 + ((lane >> 4) << 4)) ^ ((row & 7) << 4);
                    bv[kk][n] = *(const bf16x8_t*)(Bsb + row * 128 + cb);
                }
            }
            if (pf) {
                #pragma unroll
                for (int i = 0; i < aA; ++i) stageA(kt + 1, nxt, q * aA + i);
                #pragma unroll
                for (int i = 0; i < aB; ++i) stageB(kt + 1, nxt, q * aB + i);
            }
            __builtin_amdgcn_s_barrier();
            __builtin_amdgcn_s_setprio(1);
            #pragma unroll
            for (int kk = 0; kk < 2; ++kk)
                #pragma unroll
                for (int m = 0; m < 4; ++m)
                    #pragma unroll
                    for (int n = 0; n < NF; ++n)
                        acc[qm * 4 + m][qn * NF + n] = __builtin_amdgcn_mfma_f32_16x16x32_bf16(
                            af[kk][m], bv[kk][n], acc[qm * 4 + m][qn * NF + n], 0, 0, 0);
            __builtin_amdgcn_s_setprio(0);
            __builtin_amdgcn_s_barrier();
        }
        // publish next tile's staged buffer (single wait per K-tile)
        asm volatile("s_waitcnt vmcnt(0)" ::: "memory");
        __builtin_amdgcn_s_barrier();
        __builtin_amdgcn_sched_barrier(0);
    }

    // C/D layout: col = lane&15, row = (lane>>4)*4 + j
    const int r0 = mt * BM + wr * 128 + ((lane >> 4) << 2);
    const int c0 = nt * BN + wc * WCOLS + (lane & 15);
    if (GELU) {
        unsigned short* Co = (unsigned short*)C;
        #pragma unroll
        for (int m = 0; m < 8; ++m)
            #pragma unroll
            for (int n = 0; n < N_REP; ++n)
                #pragma unroll
                for (int j = 0; j < 4; ++j) {
                    float x = acc[m][n][j];
                    float u = 1.5957691216057308f * (x + 0.044715f * x * x * x);
                    float g = x / (1.f + __expf(-u));
                    Co[(size_t)(r0 + m * 16 + j) * N + (c0 + n * 16)] = f2bf(g);
                }
    } else {
        float* Co = (float*)C;
        #pragma unroll
        for (int m = 0; m < 8; ++m)
            #pragma unroll
            for (int n = 0; n < N_REP; ++n)
                #pragma unroll
                for (int j = 0; j < 4; ++j)
                    Co[(size_t)(r0 + m * 16 + j) * N + (c0 + n * 16)] = acc[m][n][j];
    }
}

extern "C" void kernel_launch(void* const* d_in, const int* in_sizes, int n_in,
                              void* d_out, int out_size, void* d_ws, size_t ws_size,
                              hipStream_t stream) {
    (void)in_sizes; (void)n_in; (void)out_size; (void)ws_size;
    const float* inp = (const float*)d_in[0];
    const float* w1  = (const float*)d_in[1];
    const float* w2  = (const float*)d_in[2];
    float* out = (float*)d_out;

    char* ws = (char*)d_ws;
    unsigned short* wbuf = (unsigned short*)ws;                                 // 64 MB (w1t, then w2t)
    unsigned short* xb   = (unsigned short*)(ws + (size_t)64 * 1024 * 1024);    // 16 MB
    unsigned short* hbuf = (unsigned short*)(ws + (size_t)80 * 1024 * 1024);    // 64 MB

    // 1) x: f32 -> bf16
    k_cvt<<<dim3((T_TOK * DMODEL / 4) / 256), 256, 0, stream>>>(
        (const float4*)inp, (ushort4*)xb, T_TOK * DMODEL / 4);

    // 2) w1 [E][D][H] -> w1t [E][H][D] bf16
    k_transpose_cvt<<<dim3(DHID / 32, DMODEL / 32, NEXP), 256, 0, stream>>>(
        w1, wbuf, DMODEL, DHID);

    // 3) h = gelu(x @ w1[e])  — 256x256 tile, 4 phases/K-tile
    k_gemm256<DMODEL, DHID, 256, 4, true>
        <<<dim3((T_TOK / 256) * (DHID / 256)), 512, 0, stream>>>(xb, wbuf, hbuf);

    // 4) w2 [E][H][D] -> w2t [E][D][H] bf16 (reuse wbuf)
    k_transpose_cvt<<<dim3(DMODEL / 32, DHID / 32, NEXP), 256, 0, stream>>>(
        w2, wbuf, DHID, DMODEL);

    // 5) out = h @ w2[e]  — 256x128 tile (grid 256 = 1 block/CU), 2 phases/K-tile
    k_gemm256<DHID, DMODEL, 128, 2, false>
        <<<dim3((T_TOK / 256) * (DMODEL / 128)), 512, 0, stream>>>(hbuf, wbuf, out);
}